// Round 21
// baseline (47.873 us; speedup 1.0000x reference)
//
#include <hip/hip_runtime.h>
#include <hip/hip_bf16.h>

#define NROWS 4096
#define IN_F 512
#define OUT_F 128
#define NBINS 128
#define NCLS 16
#define EPSV 1e-8f
#define TAUV 0.1f
#define PSTRIDE (NCLS * NBINS + 32)   // padded per-block partial stride (f32)

// C2EXP = -0.5 / sigma^2 * log2(e),  sigma = 0.2
#define C2EXP (-18.0336880f)
#define INV_STEP (12.7f)      // 127 / 10  (bins = linspace(-5,5,128))
#define WRAD 17               // window radius in bins (arg < -36 beyond)

#if defined(__has_builtin)
#if __has_builtin(__builtin_amdgcn_exp2f)
#define EXP2F(x) __builtin_amdgcn_exp2f(x)
#else
#define EXP2F(x) exp2f(x)
#endif
#else
#define EXP2F(x) exp2f(x)
#endif

typedef __attribute__((ext_vector_type(8))) short bf16x8;
typedef __attribute__((ext_vector_type(4))) float f32x4;

__device__ __forceinline__ short cvt_bf16(float x) {
    __hip_bfloat16 h = __float2bfloat16(x);
    return *reinterpret_cast<short*>(&h);
}
__device__ __forceinline__ unsigned short cvt_bf16_u(float x) {
    __hip_bfloat16 h = __float2bfloat16(x);
    return *reinterpret_cast<unsigned short*>(&h);
}

// ---------------- K0: tiled transpose + convert weights to bf16 -------------
// 20 blocks x 256 thr. Blocks 0-15: W1 (8 k-tiles x 2 n-tiles of 64x64);
// blocks 16-19: W2 (2 x 2 tiles). Coalesced reads AND writes via LDS tile.
__global__ __launch_bounds__(256) void prep_w(
    const float* __restrict__ W1, const float* __restrict__ W2,
    unsigned short* __restrict__ W1T, unsigned short* __restrict__ W2T)
{
    __shared__ unsigned short t[64][68];   // 64k x 64n tile, padded
    const int b = blockIdx.x;
    const int tid = threadIdx.x;

    const float* __restrict__ src;
    unsigned short* __restrict__ dst;
    int k0, n0, dstK;
    if (b < 16) {
        const int kt = b >> 1, nt = b & 1;
        k0 = kt * 64; n0 = nt * 64;
        src = W1; dst = W1T; dstK = IN_F;          // W1: 512k x 128n
    } else {
        const int bb = b - 16;
        const int kt = bb >> 1, nt = bb & 1;
        k0 = kt * 64; n0 = nt * 64;
        src = W2; dst = W2T; dstK = OUT_F;         // W2: 128k x 128n
    }

    // read phase: 64 rows (k) x 16 float4 (n), fully coalesced
    for (int i = tid; i < 64 * 16; i += 256) {
        const int r = i >> 4, c4 = i & 15;
        float4 v = *reinterpret_cast<const float4*>(
            src + (size_t)(k0 + r) * OUT_F + n0 + c4 * 4);
        t[c4 * 4 + 0][r] = cvt_bf16_u(v.x);
        t[c4 * 4 + 1][r] = cvt_bf16_u(v.y);
        t[c4 * 4 + 2][r] = cvt_bf16_u(v.z);
        t[c4 * 4 + 3][r] = cvt_bf16_u(v.w);
    }
    __syncthreads();

    // write phase: 64 rows (n) x 16 ushort4 (k), coalesced 8B stores
    for (int i = tid; i < 64 * 16; i += 256) {
        const int n = i >> 4, c4 = i & 15;
        ushort4 v = *reinterpret_cast<const ushort4*>(&t[n][c4 * 4]);
        *reinterpret_cast<ushort4*>(
            dst + (size_t)(n0 + n) * dstK + k0 + c4 * 4) = v;
    }
}

// ---------------- K1: fused MLP projection (MFMA) + normalize + windowed KDE
//                      + softmax + per-block class partial sums (f32).
// 512 thr = 8 waves; 16 rows/block; 512 blocks.
__global__ __launch_bounds__(512) void fused_proj_pdf(
    const float* __restrict__ X1, const float* __restrict__ X2,
    const int* __restrict__ Y1, const int* __restrict__ Y2,
    const __hip_bfloat16* __restrict__ W1T, const float* __restrict__ b1,
    const __hip_bfloat16* __restrict__ W2T, const float* __restrict__ b2,
    const float* __restrict__ bins,
    float* __restrict__ partial, float* __restrict__ pcnt)
{
    __shared__ __hip_bfloat16 xb[16][IN_F + 8];   // 16.6 KB
    __shared__ __hip_bfloat16 h_lds[16][136];     // 4.3 KB
    __shared__ float pout[16][128];               // 8 KB
    __shared__ float rowX[8][2][128];             // 8 KB normalized rows
    __shared__ float smrows[16][128];             // 8 KB softmax rows (f32)
    __shared__ float bins_s[NBINS];               // 0.5 KB
    __shared__ int   labs[16];
    const int tid  = threadIdx.x;
    const int wave = tid >> 6;      // 0..7
    const int lane = tid & 63;
    const int lr   = lane & 15;
    const int kg   = lane >> 4;
    const int row0 = blockIdx.x * 16;
    const int batch = (row0 < NROWS) ? 0 : 1;
    const float* __restrict__ X = batch ? X2 : X1;
    const int* __restrict__ Y = batch ? Y2 : Y1;
    const int xr0 = batch ? row0 - NROWS : row0;
    const int col = wave * 16 + lr;

    if (tid < NBINS) bins_s[tid] = bins[tid];
    if (tid >= 128 && tid < 144) labs[tid - 128] = Y[xr0 + tid - 128];

    // ---- Phase 0: stage X tile (16 x 512 f32 -> bf16 LDS), coalesced ----
    for (int i = tid; i < 16 * 128; i += 512) {
        const int r = i >> 7, c4 = i & 127;
        float4 v = *reinterpret_cast<const float4*>(
            X + (size_t)(xr0 + r) * IN_F + c4 * 4);
        short4 s;
        s.x = cvt_bf16(v.x); s.y = cvt_bf16(v.y);
        s.z = cvt_bf16(v.z); s.w = cvt_bf16(v.w);
        *reinterpret_cast<short4*>(&xb[r][c4 * 4]) = s;
    }
    __syncthreads();

    // ---- GEMM1: (16 x 512) * (512 x 16 per wave) ----
    f32x4 acc = {0.f, 0.f, 0.f, 0.f};
    {
        const __hip_bfloat16* __restrict__ wrow = W1T + (size_t)col * IN_F;
        #pragma unroll 4
        for (int ks = 0; ks < IN_F / 32; ++ks) {
            const int kb = ks * 32 + kg * 8;
            bf16x8 a = *reinterpret_cast<const bf16x8*>(&xb[lr][kb]);
            bf16x8 b = *reinterpret_cast<const bf16x8*>(wrow + kb);
            acc = __builtin_amdgcn_mfma_f32_16x16x32_bf16(a, b, acc, 0, 0, 0);
        }
    }
    {
        const float bb = b1[col];
        #pragma unroll
        for (int q = 0; q < 4; ++q)
            h_lds[kg * 4 + q][col] = __float2bfloat16(fmaxf(acc[q] + bb, 0.f));
    }
    __syncthreads();

    // ---- GEMM2: (16 x 128) * (128 x 16 per wave) ----
    f32x4 c2 = {0.f, 0.f, 0.f, 0.f};
    {
        const __hip_bfloat16* __restrict__ w2row = W2T + (size_t)col * OUT_F;
        #pragma unroll
        for (int ks = 0; ks < OUT_F / 32; ++ks) {
            const int kb = ks * 32 + kg * 8;
            bf16x8 a2 = *reinterpret_cast<const bf16x8*>(&h_lds[lr][kb]);
            bf16x8 b2f = *reinterpret_cast<const bf16x8*>(w2row + kb);
            c2 = __builtin_amdgcn_mfma_f32_16x16x32_bf16(a2, b2f, c2, 0, 0, 0);
        }
    }
    {
        const float cb = b2[col];
        #pragma unroll
        for (int q = 0; q < 4; ++q)
            pout[kg * 4 + q][col] = c2[q] + cb;
    }
    __syncthreads();

    // ---- PDF phase: wave handles rows {2*wave, 2*wave+1} ----
    const int m0 = wave * 2, m1 = m0 + 1;

    const float p00 = pout[m0][lane], p01 = pout[m0][lane + 64];
    const float p10 = pout[m1][lane], p11 = pout[m1][lane + 64];

    float s0 = p00 * p00 + p01 * p01;
    float s1 = p10 * p10 + p11 * p11;
    #pragma unroll
    for (int off = 32; off; off >>= 1) {
        s0 += __shfl_xor(s0, off);
        s1 += __shfl_xor(s1, off);
    }
    const float i0 = __frsqrt_rn(s0), i1 = __frsqrt_rn(s1);
    const float x00 = p00 * i0, x01 = p01 * i0;
    const float x10 = p10 * i1, x11 = p11 * i1;

    rowX[wave][0][lane]      = x00;
    rowX[wave][0][lane + 64] = x01;
    rowX[wave][1][lane]      = x10;
    rowX[wave][1][lane + 64] = x11;
    // wave-private LDS, lockstep wave64: compiler orders via lgkmcnt

    // window over both rows: |x|<=1 guarantees imax-imin <= 61 < 64
    float xlo = fminf(fminf(x00, x01), fminf(x10, x11));
    float xhi = fmaxf(fmaxf(x00, x01), fmaxf(x10, x11));
    #pragma unroll
    for (int off = 32; off; off >>= 1) {
        xlo = fminf(xlo, __shfl_xor(xlo, off));
        xhi = fmaxf(xhi, __shfl_xor(xhi, off));
    }
    int imin = (int)floorf((xlo + 5.0f) * INV_STEP) - WRAD;
    int imax = (int)ceilf ((xhi + 5.0f) * INV_STEP) + WRAD;
    imin = imin < 0 ? 0 : (imin > 127 ? 127 : imin);
    imax = imax > 127 ? 127 : (imax < 0 ? 0 : imax);
    if (imax > imin + 63) imax = imin + 63;   // provably never triggers
    const int nact = imax - imin + 1;
    const int j = imin + lane;
    const bool act = (j <= imax);
    const float bj = bins_s[act ? j : imax];

    // KDE hot loop: 2 ds_read_b128 per 8 exps; 4 accumulator chains.
    const float4* __restrict__ x0v = reinterpret_cast<const float4*>(&rowX[wave][0][0]);
    const float4* __restrict__ x1v = reinterpret_cast<const float4*>(&rowX[wave][1][0]);
    float aA0 = 0.f, aA1 = 0.f, aB0 = 0.f, aB1 = 0.f;
    #pragma unroll 4
    for (int q = 0; q < 32; ++q) {
        float4 u = x0v[q];                  // 4 dims of row0
        float4 v = x1v[q];                  // 4 dims of row1
        float t;
        t = u.x - bj; aA0 += EXP2F((C2EXP * t) * t);
        t = u.z - bj; aA1 += EXP2F((C2EXP * t) * t);
        t = v.x - bj; aB0 += EXP2F((C2EXP * t) * t);
        t = v.z - bj; aB1 += EXP2F((C2EXP * t) * t);
        t = u.y - bj; aA0 += EXP2F((C2EXP * t) * t);
        t = u.w - bj; aA1 += EXP2F((C2EXP * t) * t);
        t = v.y - bj; aB0 += EXP2F((C2EXP * t) * t);
        t = v.w - bj; aB1 += EXP2F((C2EXP * t) * t);
    }
    float pdf0 = act ? (aA0 + aA1) * (1.0f / OUT_F) : 0.f;
    float pdf1 = act ? (aB0 + aB1) * (1.0f / OUT_F) : 0.f;

    // normalize over all 128 bins (out-of-window bins are exactly 0)
    float t0 = pdf0, t1 = pdf1;
    #pragma unroll
    for (int off = 32; off; off >>= 1) {
        t0 += __shfl_xor(t0, off);
        t1 += __shfl_xor(t1, off);
    }
    pdf0 *= 1.0f / (t0 + EPSV);
    pdf1 *= 1.0f / (t1 + EPSV);

    // softmax max: values >= 0 and zero-bins are 0, so plain max works
    float mx0 = pdf0, mx1 = pdf1;
    #pragma unroll
    for (int off = 32; off; off >>= 1) {
        mx0 = fmaxf(mx0, __shfl_xor(mx0, off));
        mx1 = fmaxf(mx1, __shfl_xor(mx1, off));
    }
    const float q0 = act ? __expf(pdf0 - mx0) : 0.f;
    const float q1 = act ? __expf(pdf1 - mx1) : 0.f;
    const float ez0 = __expf(-mx0), ez1 = __expf(-mx1);
    float es0 = q0, es1 = q1;
    #pragma unroll
    for (int off = 32; off; off >>= 1) {
        es0 += __shfl_xor(es0, off);
        es1 += __shfl_xor(es1, off);
    }
    es0 += (float)(NBINS - nact) * ez0;
    es1 += (float)(NBINS - nact) * ez1;
    const float r0 = 1.0f / es0, r1 = 1.0f / es1;
    const float z0 = ez0 * r0, z1 = ez1 * r1;

    // scatter windowed values to output bins {lane, lane+64} -> LDS (f32)
    const int sa = lane - imin;
    const int sb = lane + 64 - imin;
    const float w0a = __shfl(q0, sa & 63) * r0;
    const float w0b = __shfl(q0, sb & 63) * r0;
    const float w1a = __shfl(q1, sa & 63) * r1;
    const float w1b = __shfl(q1, sb & 63) * r1;
    const bool ina = (unsigned)sa < (unsigned)nact;
    const bool inb = (unsigned)sb < (unsigned)nact;

    smrows[m0][lane]      = ina ? w0a : z0;
    smrows[m0][lane + 64] = inb ? w0b : z0;
    smrows[m1][lane]      = ina ? w1a : z1;
    smrows[m1][lane + 64] = inb ? w1b : z1;
    __syncthreads();

    // ---- classsum: thread = (class, j-quad); 16 rows, predicated fma ----
    {
        const int c_cls = tid >> 5;       // 0..15
        const int jq    = tid & 31;       // 0..31
        f32x4 accp = {0.f, 0.f, 0.f, 0.f};
        int ccnt = 0;
        #pragma unroll 4
        for (int r = 0; r < 16; ++r) {
            const float4 v = *reinterpret_cast<const float4*>(&smrows[r][jq * 4]);
            const float h = (labs[r] == c_cls) ? 1.f : 0.f;
            accp.x = fmaf(h, v.x, accp.x);
            accp.y = fmaf(h, v.y, accp.y);
            accp.z = fmaf(h, v.z, accp.z);
            accp.w = fmaf(h, v.w, accp.w);
            ccnt += (labs[r] == c_cls);
        }
        *reinterpret_cast<f32x4*>(
            &partial[(size_t)blockIdx.x * PSTRIDE + c_cls * NBINS + jq * 4]) = accp;
        if (jq == 0) pcnt[(size_t)blockIdx.x * NCLS + c_cls] = (float)ccnt;
    }
}

// ---------------- K2: merge 256 per-block partials per batch -> dist --------
// 256 blocks = (bc 0..31, jg 0..7); 256 threads = (s 0..15, jl 0..15).
__global__ __launch_bounds__(256) void merge_kernel(
    const float* __restrict__ partial, const float* __restrict__ pcnt,
    float* __restrict__ dist, float* __restrict__ cntg)
{
    __shared__ float sd[16][17];     // +1 pad
    __shared__ float sc[4];
    const int b = blockIdx.x;             // 0..255
    const int bc = b >> 3, jg = b & 7;
    const int batch = bc >> 4, c = bc & 15;
    const int j0 = jg * 16;
    const int tid = threadIdx.x;
    const int jl = tid & 15, s = tid >> 4;   // s 0..15

    // each thread sums 16 of the 256 per-block partials (short chains)
    float acc = 0.f;
    #pragma unroll 4
    for (int k = 0; k < 16; ++k) {
        const int sb = s + k * 16;           // source block within batch
        acc += partial[(size_t)(batch * 256 + sb) * PSTRIDE + c * NBINS + j0 + jl];
    }
    sd[s][jl] = acc;

    // counts (computed by all blocks; written only by jg==0)
    float cv = pcnt[(size_t)(batch * 256 + tid) * NCLS + c];
    #pragma unroll
    for (int off = 32; off; off >>= 1) cv += __shfl_xor(cv, off);
    if ((tid & 63) == 0) sc[tid >> 6] = cv;
    __syncthreads();

    if (tid < 16) {
        float d = 0.f;
        #pragma unroll
        for (int q = 0; q < 16; ++q) d += sd[q][tid];
        dist[(size_t)bc * NBINS + j0 + tid] = d;
    }
    if (jg == 0 && tid == 0) cntg[bc] = sc[0] + sc[1] + sc[2] + sc[3];
}

// ---------------- K3: means, logs, tiled KL, loss ---------------------------
// Unified 32-row arrays: rows 0-15 = class means, rows 16-31 = mixture M.
__global__ __launch_bounds__(512) void final_kernel(
    const float* __restrict__ dist, const float* __restrict__ cntg,
    float* __restrict__ out)
{
    __shared__ float P_A[32][132], L_A[32][132];   // 2 x 16.5 KB
    __shared__ float P_B[32][132], L_B[32][132];   // 2 x 16.5 KB
    __shared__ float JA[32][32], JB[32][32];       // 8 KB
    __shared__ float pls[32];
    __shared__ float cnt[32];
    __shared__ float HA[32], HB[32];
    const int tid = threadIdx.x;

    if (tid < 32) cnt[tid] = cntg[tid];
    __syncthreads();

    // means, mixture (rows 16-31), logs (mixture log computed once)
    for (int s = tid; s < NCLS * NBINS; s += 512) {
        const int c = s >> 7, jj = s & 127;
        const float a = dist[(size_t)c * NBINS + jj] / cnt[c];
        const float b = dist[(size_t)(16 + c) * NBINS + jj] / cnt[16 + c];
        const float mm = 0.5f * (a + b);
        const float lm = __logf(mm);
        P_A[c][jj] = a;        L_A[c][jj] = __logf(a);
        P_A[c + 16][jj] = mm;  L_A[c + 16][jj] = lm;
        P_B[c][jj] = b;        L_B[c][jj] = __logf(b);
        P_B[c + 16][jj] = mm;  L_B[c + 16][jj] = lm;
    }
    __syncthreads();

    // self terms H[i] = sum_j P[i][j] * L[i][j], float4 reads
    if (tid < 64) {
        const int i = tid & 31;
        const float4* Pv = reinterpret_cast<const float4*>(
            (tid < 32) ? &P_A[i][0] : &P_B[i][0]);
        const float4* Lv = reinterpret_cast<const float4*>(
            (tid < 32) ? &L_A[i][0] : &L_B[i][0]);
        float h = 0.f;
        #pragma unroll 4
        for (int q = 0; q < 32; ++q) {
            float4 p = Pv[q], l = Lv[q];
            h = fmaf(p.x, l.x, h); h = fmaf(p.y, l.y, h);
            h = fmaf(p.z, l.z, h); h = fmaf(p.w, l.w, h);
        }
        if (tid < 32) HA[i] = h; else HB[i] = h;
    }
    __syncthreads();

    // KL cross terms: 4x4 register tile per thread, float4 LDS reads.
    if (tid < 128) {
        const int side = tid >> 6;
        const int t = tid & 63;
        const int i0 = (t >> 3) << 2, k0 = (t & 7) << 2;
        const float4* pr[4];
        const float4* lq[4];
        #pragma unroll
        for (int a = 0; a < 4; ++a) {
            pr[a] = reinterpret_cast<const float4*>(
                side ? &P_B[i0 + a][0] : &P_A[i0 + a][0]);
            lq[a] = reinterpret_cast<const float4*>(
                side ? &L_B[k0 + a][0] : &L_A[k0 + a][0]);
        }
        float accv[4][4];
        #pragma unroll
        for (int a = 0; a < 4; ++a)
            #pragma unroll
            for (int b = 0; b < 4; ++b) accv[a][b] = 0.f;
        for (int q = 0; q < 32; ++q) {
            float4 Pv[4], Lv[4];
            #pragma unroll
            for (int a = 0; a < 4; ++a) { Pv[a] = pr[a][q]; Lv[a] = lq[a][q]; }
            #pragma unroll
            for (int a = 0; a < 4; ++a)
                #pragma unroll
                for (int b = 0; b < 4; ++b) {
                    accv[a][b] = fmaf(Pv[a].x, Lv[b].x, accv[a][b]);
                    accv[a][b] = fmaf(Pv[a].y, Lv[b].y, accv[a][b]);
                    accv[a][b] = fmaf(Pv[a].z, Lv[b].z, accv[a][b]);
                    accv[a][b] = fmaf(Pv[a].w, Lv[b].w, accv[a][b]);
                }
        }
        float (*Jout)[32] = side ? JB : JA;
        #pragma unroll
        for (int a = 0; a < 4; ++a)
            #pragma unroll
            for (int b = 0; b < 4; ++b)
                Jout[i0 + a][k0 + b] = accv[a][b];
    }
    __syncthreads();

    // combine: J[i][k] = 0.5*((HA[i]-crossA) + (HB[i]-crossB)), diag = 0
    for (int p = tid; p < 32 * 32; p += 512) {
        const int i = p >> 5, k = p & 31;
        const float Jv = (i == k) ? 0.f
            : 0.5f * ((HA[i] - JA[i][k]) + (HB[i] - JB[i][k]));
        JA[i][k] = Jv;
    }
    __syncthreads();

    if (tid < 32) {
        float den = 0.f;
        for (int k = 0; k < 32; ++k) den += __expf(JA[tid][k] * (1.0f / TAUV));
        const float pos = JA[tid][(tid + 16) & 31];
        pls[tid] = -(pos * (1.0f / TAUV)) + __logf(den);
    }
    __syncthreads();
    if (tid == 0) {
        float s = 0.f;
        for (int i = 0; i < 32; ++i) s += pls[i];
        out[0] = s * (1.0f / 32.0f);
    }
}

extern "C" void kernel_launch(void* const* d_in, const int* in_sizes, int n_in,
                              void* d_out, int out_size, void* d_ws, size_t ws_size,
                              hipStream_t stream)
{
    const float* x1   = (const float*)d_in[0];
    const int*   y1   = (const int*)d_in[1];
    const float* x2   = (const float*)d_in[2];
    const int*   y2   = (const int*)d_in[3];
    const float* W1   = (const float*)d_in[4];
    const float* b1   = (const float*)d_in[5];
    const float* W2   = (const float*)d_in[6];
    const float* b2   = (const float*)d_in[7];
    const float* bins = (const float*)d_in[8];
    float* out = (float*)d_out;

    char* ws = (char*)d_ws;
    float* partial = (float*)ws;                                   // 512*PSTRIDE*4 ≈ 4.3 MB
    float* pcnt    = partial + (size_t)512 * PSTRIDE;              // 512*16 f32
    float* dist    = pcnt + 512 * NCLS;                            // 32*128 f32
    float* cntg    = dist + 32 * NBINS;                            // 32 f32
    unsigned short* W1T = (unsigned short*)(cntg + 64);
    unsigned short* W2T = W1T + (size_t)OUT_F * IN_F;

    prep_w<<<20, 256, 0, stream>>>(W1, W2, W1T, W2T);
    fused_proj_pdf<<<512, 512, 0, stream>>>(x1, x2, y1, y2,
                                            (const __hip_bfloat16*)W1T, b1,
                                            (const __hip_bfloat16*)W2T, b2,
                                            bins, partial, pcnt);
    merge_kernel<<<256, 256, 0, stream>>>(partial, pcnt, dist, cntg);
    final_kernel<<<1, 512, 0, stream>>>(dist, cntg, out);
}

// Round 22
// 45.970 us; speedup vs baseline: 1.0414x; 1.0414x over previous
//
#include <hip/hip_runtime.h>
#include <hip/hip_bf16.h>

#define NROWS 4096
#define IN_F 512
#define OUT_F 128
#define NBINS 128
#define NCLS 16
#define EPSV 1e-8f
#define TAUV 0.1f
#define PSTRIDE (NCLS * NBINS + 32)   // padded per-block partial stride (f32)

// C2EXP = -0.5 / sigma^2 * log2(e),  sigma = 0.2
#define C2EXP (-18.0336880f)
#define M2C   (36.0673760f)   // -2 * C2EXP
#define INV_STEP (12.7f)      // 127 / 10  (bins = linspace(-5,5,128))
#define WRAD 17               // window radius in bins (arg < -36 beyond)

#if defined(__has_builtin)
#if __has_builtin(__builtin_amdgcn_exp2f)
#define EXP2F(x) __builtin_amdgcn_exp2f(x)
#else
#define EXP2F(x) exp2f(x)
#endif
#else
#define EXP2F(x) exp2f(x)
#endif

typedef __attribute__((ext_vector_type(8))) short bf16x8;
typedef __attribute__((ext_vector_type(4))) float f32x4;
typedef __attribute__((ext_vector_type(2))) float f32x2;

__device__ __forceinline__ short cvt_bf16(float x) {
    __hip_bfloat16 h = __float2bfloat16(x);
    return *reinterpret_cast<short*>(&h);
}
__device__ __forceinline__ unsigned short cvt_bf16_u(float x) {
    __hip_bfloat16 h = __float2bfloat16(x);
    return *reinterpret_cast<unsigned short*>(&h);
}

// ---------------- K0: tiled transpose + convert weights to bf16 -------------
__global__ __launch_bounds__(256) void prep_w(
    const float* __restrict__ W1, const float* __restrict__ W2,
    unsigned short* __restrict__ W1T, unsigned short* __restrict__ W2T)
{
    __shared__ unsigned short t[64][68];   // 64k x 64n tile, padded
    const int b = blockIdx.x;
    const int tid = threadIdx.x;

    const float* __restrict__ src;
    unsigned short* __restrict__ dst;
    int k0, n0, dstK;
    if (b < 16) {
        const int kt = b >> 1, nt = b & 1;
        k0 = kt * 64; n0 = nt * 64;
        src = W1; dst = W1T; dstK = IN_F;          // W1: 512k x 128n
    } else {
        const int bb = b - 16;
        const int kt = bb >> 1, nt = bb & 1;
        k0 = kt * 64; n0 = nt * 64;
        src = W2; dst = W2T; dstK = OUT_F;         // W2: 128k x 128n
    }

    for (int i = tid; i < 64 * 16; i += 256) {
        const int r = i >> 4, c4 = i & 15;
        float4 v = *reinterpret_cast<const float4*>(
            src + (size_t)(k0 + r) * OUT_F + n0 + c4 * 4);
        t[c4 * 4 + 0][r] = cvt_bf16_u(v.x);
        t[c4 * 4 + 1][r] = cvt_bf16_u(v.y);
        t[c4 * 4 + 2][r] = cvt_bf16_u(v.z);
        t[c4 * 4 + 3][r] = cvt_bf16_u(v.w);
    }
    __syncthreads();

    for (int i = tid; i < 64 * 16; i += 256) {
        const int n = i >> 4, c4 = i & 15;
        ushort4 v = *reinterpret_cast<const ushort4*>(&t[n][c4 * 4]);
        *reinterpret_cast<ushort4*>(
            dst + (size_t)(n0 + n) * dstK + k0 + c4 * 4) = v;
    }
}

// ---------------- K1: fused MLP projection (MFMA) + normalize + windowed KDE
//                      + softmax + per-block class partial sums (f32).
// 512 thr = 8 waves; 16 rows/block; 512 blocks.
// KDE uses per-dim float4 (m_r0, m_r1, A_r0, A_r1) table + packed f32 math.
__global__ __launch_bounds__(512) void fused_proj_pdf(
    const float* __restrict__ X1, const float* __restrict__ X2,
    const int* __restrict__ Y1, const int* __restrict__ Y2,
    const __hip_bfloat16* __restrict__ W1T, const float* __restrict__ b1,
    const __hip_bfloat16* __restrict__ W2T, const float* __restrict__ b2,
    const float* __restrict__ bins,
    float* __restrict__ partial, float* __restrict__ pcnt)
{
    __shared__ __hip_bfloat16 xb[16][IN_F + 8];   // 16.6 KB
    __shared__ __hip_bfloat16 h_lds[16][136];     // 4.3 KB
    __shared__ float pout[16][128];               // 8 KB
    __shared__ f32x4 rowMA[8][128];               // 16 KB (m0,m1,A0,A1) per dim
    __shared__ float smrows[16][128];             // 8 KB softmax rows (f32)
    __shared__ float bins_s[NBINS];               // 0.5 KB
    __shared__ int   labs[16];
    const int tid  = threadIdx.x;
    const int wave = tid >> 6;      // 0..7
    const int lane = tid & 63;
    const int lr   = lane & 15;
    const int kg   = lane >> 4;
    const int row0 = blockIdx.x * 16;
    const int batch = (row0 < NROWS) ? 0 : 1;
    const float* __restrict__ X = batch ? X2 : X1;
    const int* __restrict__ Y = batch ? Y2 : Y1;
    const int xr0 = batch ? row0 - NROWS : row0;
    const int col = wave * 16 + lr;

    if (tid < NBINS) bins_s[tid] = bins[tid];
    if (tid >= 128 && tid < 144) labs[tid - 128] = Y[xr0 + tid - 128];

    // ---- Phase 0: stage X tile (16 x 512 f32 -> bf16 LDS), coalesced ----
    for (int i = tid; i < 16 * 128; i += 512) {
        const int r = i >> 7, c4 = i & 127;
        float4 v = *reinterpret_cast<const float4*>(
            X + (size_t)(xr0 + r) * IN_F + c4 * 4);
        short4 s;
        s.x = cvt_bf16(v.x); s.y = cvt_bf16(v.y);
        s.z = cvt_bf16(v.z); s.w = cvt_bf16(v.w);
        *reinterpret_cast<short4*>(&xb[r][c4 * 4]) = s;
    }
    __syncthreads();

    // ---- GEMM1: (16 x 512) * (512 x 16 per wave) ----
    f32x4 acc = {0.f, 0.f, 0.f, 0.f};
    {
        const __hip_bfloat16* __restrict__ wrow = W1T + (size_t)col * IN_F;
        #pragma unroll 4
        for (int ks = 0; ks < IN_F / 32; ++ks) {
            const int kb = ks * 32 + kg * 8;
            bf16x8 a = *reinterpret_cast<const bf16x8*>(&xb[lr][kb]);
            bf16x8 b = *reinterpret_cast<const bf16x8*>(wrow + kb);
            acc = __builtin_amdgcn_mfma_f32_16x16x32_bf16(a, b, acc, 0, 0, 0);
        }
    }
    {
        const float bb = b1[col];
        #pragma unroll
        for (int q = 0; q < 4; ++q)
            h_lds[kg * 4 + q][col] = __float2bfloat16(fmaxf(acc[q] + bb, 0.f));
    }
    __syncthreads();

    // ---- GEMM2: (16 x 128) * (128 x 16 per wave) ----
    f32x4 c2 = {0.f, 0.f, 0.f, 0.f};
    {
        const __hip_bfloat16* __restrict__ w2row = W2T + (size_t)col * OUT_F;
        #pragma unroll
        for (int ks = 0; ks < OUT_F / 32; ++ks) {
            const int kb = ks * 32 + kg * 8;
            bf16x8 a2 = *reinterpret_cast<const bf16x8*>(&h_lds[lr][kb]);
            bf16x8 b2f = *reinterpret_cast<const bf16x8*>(w2row + kb);
            c2 = __builtin_amdgcn_mfma_f32_16x16x32_bf16(a2, b2f, c2, 0, 0, 0);
        }
    }
    {
        const float cb = b2[col];
        #pragma unroll
        for (int q = 0; q < 4; ++q)
            pout[kg * 4 + q][col] = c2[q] + cb;
    }
    __syncthreads();

    // ---- PDF phase: wave handles rows {2*wave, 2*wave+1} ----
    const int m0 = wave * 2, m1 = m0 + 1;

    const float p00 = pout[m0][lane], p01 = pout[m0][lane + 64];
    const float p10 = pout[m1][lane], p11 = pout[m1][lane + 64];

    float s0 = p00 * p00 + p01 * p01;
    float s1 = p10 * p10 + p11 * p11;
    #pragma unroll
    for (int off = 32; off; off >>= 1) {
        s0 += __shfl_xor(s0, off);
        s1 += __shfl_xor(s1, off);
    }
    const float i0 = __frsqrt_rn(s0), i1 = __frsqrt_rn(s1);
    const float x00 = p00 * i0, x01 = p01 * i0;
    const float x10 = p10 * i1, x11 = p11 * i1;

    // per-dim table: (m_r0, m_r1, A_r0, A_r1); arg_r = m_r*bj + (A_r + Bj)
    rowMA[wave][lane]      = (f32x4){x00 * M2C, x10 * M2C,
                                     C2EXP * x00 * x00, C2EXP * x10 * x10};
    rowMA[wave][lane + 64] = (f32x4){x01 * M2C, x11 * M2C,
                                     C2EXP * x01 * x01, C2EXP * x11 * x11};
    // wave-private LDS, lockstep wave64: compiler orders via lgkmcnt

    // window over both rows: |x|<=1 guarantees imax-imin <= 61 < 64
    float xlo = fminf(fminf(x00, x01), fminf(x10, x11));
    float xhi = fmaxf(fmaxf(x00, x01), fmaxf(x10, x11));
    #pragma unroll
    for (int off = 32; off; off >>= 1) {
        xlo = fminf(xlo, __shfl_xor(xlo, off));
        xhi = fmaxf(xhi, __shfl_xor(xhi, off));
    }
    int imin = (int)floorf((xlo + 5.0f) * INV_STEP) - WRAD;
    int imax = (int)ceilf ((xhi + 5.0f) * INV_STEP) + WRAD;
    imin = imin < 0 ? 0 : (imin > 127 ? 127 : imin);
    imax = imax > 127 ? 127 : (imax < 0 ? 0 : imax);
    if (imax > imin + 63) imax = imin + 63;   // provably never triggers
    const int nact = imax - imin + 1;
    const int j = imin + lane;
    const bool act = (j <= imax);
    const float bj = bins_s[act ? j : imax];
    const float Bj = C2EXP * bj * bj;
    const f32x2 BJ2 = {bj, bj};
    const f32x2 BB2 = {Bj, Bj};

    // KDE hot loop: per dim = 1 b128 read, pk_add, pk_fma, 2 exp, pk_acc.
    const f32x4* __restrict__ tb = &rowMA[wave][0];
    f32x2 accP = {0.f, 0.f};      // rows 0,1 accumulator (packed)
    f32x2 accQ = {0.f, 0.f};      // second chain
    #pragma unroll 8
    for (int d = 0; d < 128; d += 2) {
        f32x4 e0 = tb[d];                       // (m0, m1, A0, A1) dim d
        f32x4 e1 = tb[d + 1];                   // dim d+1
        f32x2 g0 = (f32x2){e0[0], e0[1]} * BJ2 + ((f32x2){e0[2], e0[3]} + BB2);
        f32x2 g1 = (f32x2){e1[0], e1[1]} * BJ2 + ((f32x2){e1[2], e1[3]} + BB2);
        accP += (f32x2){EXP2F(g0.x), EXP2F(g0.y)};
        accQ += (f32x2){EXP2F(g1.x), EXP2F(g1.y)};
    }
    float pdf0 = act ? (accP.x + accQ.x) * (1.0f / OUT_F) : 0.f;
    float pdf1 = act ? (accP.y + accQ.y) * (1.0f / OUT_F) : 0.f;

    // normalize over all 128 bins (out-of-window bins are exactly 0)
    float t0 = pdf0, t1 = pdf1;
    #pragma unroll
    for (int off = 32; off; off >>= 1) {
        t0 += __shfl_xor(t0, off);
        t1 += __shfl_xor(t1, off);
    }
    pdf0 *= 1.0f / (t0 + EPSV);
    pdf1 *= 1.0f / (t1 + EPSV);

    // softmax max: values >= 0 and zero-bins are 0, so plain max works
    float mx0 = pdf0, mx1 = pdf1;
    #pragma unroll
    for (int off = 32; off; off >>= 1) {
        mx0 = fmaxf(mx0, __shfl_xor(mx0, off));
        mx1 = fmaxf(mx1, __shfl_xor(mx1, off));
    }
    const float q0 = act ? __expf(pdf0 - mx0) : 0.f;
    const float q1 = act ? __expf(pdf1 - mx1) : 0.f;
    const float ez0 = __expf(-mx0), ez1 = __expf(-mx1);
    float es0 = q0, es1 = q1;
    #pragma unroll
    for (int off = 32; off; off >>= 1) {
        es0 += __shfl_xor(es0, off);
        es1 += __shfl_xor(es1, off);
    }
    es0 += (float)(NBINS - nact) * ez0;
    es1 += (float)(NBINS - nact) * ez1;
    const float r0 = 1.0f / es0, r1 = 1.0f / es1;
    const float z0 = ez0 * r0, z1 = ez1 * r1;

    // scatter windowed values to output bins {lane, lane+64} -> LDS (f32)
    const int sa = lane - imin;
    const int sb = lane + 64 - imin;
    const float w0a = __shfl(q0, sa & 63) * r0;
    const float w0b = __shfl(q0, sb & 63) * r0;
    const float w1a = __shfl(q1, sa & 63) * r1;
    const float w1b = __shfl(q1, sb & 63) * r1;
    const bool ina = (unsigned)sa < (unsigned)nact;
    const bool inb = (unsigned)sb < (unsigned)nact;

    smrows[m0][lane]      = ina ? w0a : z0;
    smrows[m0][lane + 64] = inb ? w0b : z0;
    smrows[m1][lane]      = ina ? w1a : z1;
    smrows[m1][lane + 64] = inb ? w1b : z1;
    __syncthreads();

    // ---- classsum: thread = (class, j-quad); 16 rows, predicated fma ----
    {
        const int c_cls = tid >> 5;       // 0..15
        const int jq    = tid & 31;       // 0..31
        f32x4 accp = {0.f, 0.f, 0.f, 0.f};
        int ccnt = 0;
        #pragma unroll 4
        for (int r = 0; r < 16; ++r) {
            const float4 v = *reinterpret_cast<const float4*>(&smrows[r][jq * 4]);
            const float h = (labs[r] == c_cls) ? 1.f : 0.f;
            accp.x = fmaf(h, v.x, accp.x);
            accp.y = fmaf(h, v.y, accp.y);
            accp.z = fmaf(h, v.z, accp.z);
            accp.w = fmaf(h, v.w, accp.w);
            ccnt += (labs[r] == c_cls);
        }
        *reinterpret_cast<f32x4*>(
            &partial[(size_t)blockIdx.x * PSTRIDE + c_cls * NBINS + jq * 4]) = accp;
        if (jq == 0) pcnt[(size_t)blockIdx.x * NCLS + c_cls] = (float)ccnt;
    }
}

// ---------------- K2: merge 256 per-block partials per batch -> dist --------
__global__ __launch_bounds__(256) void merge_kernel(
    const float* __restrict__ partial, const float* __restrict__ pcnt,
    float* __restrict__ dist, float* __restrict__ cntg)
{
    __shared__ float sd[16][17];     // +1 pad
    __shared__ float sc[4];
    const int b = blockIdx.x;             // 0..255
    const int bc = b >> 3, jg = b & 7;
    const int batch = bc >> 4, c = bc & 15;
    const int j0 = jg * 16;
    const int tid = threadIdx.x;
    const int jl = tid & 15, s = tid >> 4;   // s 0..15

    float acc = 0.f;
    #pragma unroll 4
    for (int k = 0; k < 16; ++k) {
        const int sb = s + k * 16;           // source block within batch
        acc += partial[(size_t)(batch * 256 + sb) * PSTRIDE + c * NBINS + j0 + jl];
    }
    sd[s][jl] = acc;

    float cv = pcnt[(size_t)(batch * 256 + tid) * NCLS + c];
    #pragma unroll
    for (int off = 32; off; off >>= 1) cv += __shfl_xor(cv, off);
    if ((tid & 63) == 0) sc[tid >> 6] = cv;
    __syncthreads();

    if (tid < 16) {
        float d = 0.f;
        #pragma unroll
        for (int q = 0; q < 16; ++q) d += sd[q][tid];
        dist[(size_t)bc * NBINS + j0 + tid] = d;
    }
    if (jg == 0 && tid == 0) cntg[bc] = sc[0] + sc[1] + sc[2] + sc[3];
}

// ---------------- K3: means, logs, tiled KL, loss ---------------------------
__global__ __launch_bounds__(512) void final_kernel(
    const float* __restrict__ dist, const float* __restrict__ cntg,
    float* __restrict__ out)
{
    __shared__ float P_A[32][132], L_A[32][132];   // 2 x 16.5 KB
    __shared__ float P_B[32][132], L_B[32][132];   // 2 x 16.5 KB
    __shared__ float JA[32][32], JB[32][32];       // 8 KB
    __shared__ float pls[32];
    __shared__ float cnt[32];
    __shared__ float HA[32], HB[32];
    const int tid = threadIdx.x;

    if (tid < 32) cnt[tid] = cntg[tid];
    __syncthreads();

    for (int s = tid; s < NCLS * NBINS; s += 512) {
        const int c = s >> 7, jj = s & 127;
        const float a = dist[(size_t)c * NBINS + jj] / cnt[c];
        const float b = dist[(size_t)(16 + c) * NBINS + jj] / cnt[16 + c];
        const float mm = 0.5f * (a + b);
        const float lm = __logf(mm);
        P_A[c][jj] = a;        L_A[c][jj] = __logf(a);
        P_A[c + 16][jj] = mm;  L_A[c + 16][jj] = lm;
        P_B[c][jj] = b;        L_B[c][jj] = __logf(b);
        P_B[c + 16][jj] = mm;  L_B[c + 16][jj] = lm;
    }
    __syncthreads();

    if (tid < 64) {
        const int i = tid & 31;
        const float4* Pv = reinterpret_cast<const float4*>(
            (tid < 32) ? &P_A[i][0] : &P_B[i][0]);
        const float4* Lv = reinterpret_cast<const float4*>(
            (tid < 32) ? &L_A[i][0] : &L_B[i][0]);
        float h = 0.f;
        #pragma unroll 4
        for (int q = 0; q < 32; ++q) {
            float4 p = Pv[q], l = Lv[q];
            h = fmaf(p.x, l.x, h); h = fmaf(p.y, l.y, h);
            h = fmaf(p.z, l.z, h); h = fmaf(p.w, l.w, h);
        }
        if (tid < 32) HA[i] = h; else HB[i] = h;
    }
    __syncthreads();

    if (tid < 128) {
        const int side = tid >> 6;
        const int t = tid & 63;
        const int i0 = (t >> 3) << 2, k0 = (t & 7) << 2;
        const float4* pr[4];
        const float4* lq[4];
        #pragma unroll
        for (int a = 0; a < 4; ++a) {
            pr[a] = reinterpret_cast<const float4*>(
                side ? &P_B[i0 + a][0] : &P_A[i0 + a][0]);
            lq[a] = reinterpret_cast<const float4*>(
                side ? &L_B[k0 + a][0] : &L_A[k0 + a][0]);
        }
        float accv[4][4];
        #pragma unroll
        for (int a = 0; a < 4; ++a)
            #pragma unroll
            for (int b = 0; b < 4; ++b) accv[a][b] = 0.f;
        for (int q = 0; q < 32; ++q) {
            float4 Pv[4], Lv[4];
            #pragma unroll
            for (int a = 0; a < 4; ++a) { Pv[a] = pr[a][q]; Lv[a] = lq[a][q]; }
            #pragma unroll
            for (int a = 0; a < 4; ++a)
                #pragma unroll
                for (int b = 0; b < 4; ++b) {
                    accv[a][b] = fmaf(Pv[a].x, Lv[b].x, accv[a][b]);
                    accv[a][b] = fmaf(Pv[a].y, Lv[b].y, accv[a][b]);
                    accv[a][b] = fmaf(Pv[a].z, Lv[b].z, accv[a][b]);
                    accv[a][b] = fmaf(Pv[a].w, Lv[b].w, accv[a][b]);
                }
        }
        float (*Jout)[32] = side ? JB : JA;
        #pragma unroll
        for (int a = 0; a < 4; ++a)
            #pragma unroll
            for (int b = 0; b < 4; ++b)
                Jout[i0 + a][k0 + b] = accv[a][b];
    }
    __syncthreads();

    for (int p = tid; p < 32 * 32; p += 512) {
        const int i = p >> 5, k = p & 31;
        const float Jv = (i == k) ? 0.f
            : 0.5f * ((HA[i] - JA[i][k]) + (HB[i] - JB[i][k]));
        JA[i][k] = Jv;
    }
    __syncthreads();

    if (tid < 32) {
        float den = 0.f;
        for (int k = 0; k < 32; ++k) den += __expf(JA[tid][k] * (1.0f / TAUV));
        const float pos = JA[tid][(tid + 16) & 31];
        pls[tid] = -(pos * (1.0f / TAUV)) + __logf(den);
    }
    __syncthreads();
    if (tid == 0) {
        float s = 0.f;
        for (int i = 0; i < 32; ++i) s += pls[i];
        out[0] = s * (1.0f / 32.0f);
    }
}

extern "C" void kernel_launch(void* const* d_in, const int* in_sizes, int n_in,
                              void* d_out, int out_size, void* d_ws, size_t ws_size,
                              hipStream_t stream)
{
    const float* x1   = (const float*)d_in[0];
    const int*   y1   = (const int*)d_in[1];
    const float* x2   = (const float*)d_in[2];
    const int*   y2   = (const int*)d_in[3];
    const float* W1   = (const float*)d_in[4];
    const float* b1   = (const float*)d_in[5];
    const float* W2   = (const float*)d_in[6];
    const float* b2   = (const float*)d_in[7];
    const float* bins = (const float*)d_in[8];
    float* out = (float*)d_out;

    char* ws = (char*)d_ws;
    float* partial = (float*)ws;                                   // 512*PSTRIDE*4 ≈ 4.3 MB
    float* pcnt    = partial + (size_t)512 * PSTRIDE;              // 512*16 f32
    float* dist    = pcnt + 512 * NCLS;                            // 32*128 f32
    float* cntg    = dist + 32 * NBINS;                            // 32 f32
    unsigned short* W1T = (unsigned short*)(cntg + 64);
    unsigned short* W2T = W1T + (size_t)OUT_F * IN_F;

    prep_w<<<20, 256, 0, stream>>>(W1, W2, W1T, W2T);
    fused_proj_pdf<<<512, 512, 0, stream>>>(x1, x2, y1, y2,
                                            (const __hip_bfloat16*)W1T, b1,
                                            (const __hip_bfloat16*)W2T, b2,
                                            bins, partial, pcnt);
    merge_kernel<<<256, 256, 0, stream>>>(partial, pcnt, dist, cntg);
    final_kernel<<<1, 512, 0, stream>>>(dist, cntg, out);
}

// Round 23
// 44.530 us; speedup vs baseline: 1.0751x; 1.0323x over previous
//
#include <hip/hip_runtime.h>
#include <hip/hip_bf16.h>

#define NROWS 4096
#define IN_F 512
#define OUT_F 128
#define NBINS 128
#define NCLS 16
#define EPSV 1e-8f
#define TAUV 0.1f
#define PSTRIDE (NCLS * NBINS + 32)   // padded per-block partial stride (f32)

// C2EXP = -0.5 / sigma^2 * log2(e),  sigma = 0.2
#define C2EXP (-18.0336880f)
#define M2C   (36.0673760f)   // -2 * C2EXP
#define INV_STEP (12.7f)      // 127 / 10  (bins = linspace(-5,5,128))
#define WRAD 17               // window radius in bins (arg < -36 beyond)

#if defined(__has_builtin)
#if __has_builtin(__builtin_amdgcn_exp2f)
#define EXP2F(x) __builtin_amdgcn_exp2f(x)
#else
#define EXP2F(x) exp2f(x)
#endif
#else
#define EXP2F(x) exp2f(x)
#endif

typedef __attribute__((ext_vector_type(8))) short bf16x8;
typedef __attribute__((ext_vector_type(4))) float f32x4;
typedef __attribute__((ext_vector_type(2))) float f32x2;

__device__ __forceinline__ short cvt_bf16(float x) {
    __hip_bfloat16 h = __float2bfloat16(x);
    return *reinterpret_cast<short*>(&h);
}
__device__ __forceinline__ unsigned short cvt_bf16_u(float x) {
    __hip_bfloat16 h = __float2bfloat16(x);
    return *reinterpret_cast<unsigned short*>(&h);
}

// ---------------- K0: tiled transpose + convert weights to bf16 -------------
__global__ __launch_bounds__(256) void prep_w(
    const float* __restrict__ W1, const float* __restrict__ W2,
    unsigned short* __restrict__ W1T, unsigned short* __restrict__ W2T)
{
    __shared__ unsigned short t[64][68];   // 64k x 64n tile, padded
    const int b = blockIdx.x;
    const int tid = threadIdx.x;

    const float* __restrict__ src;
    unsigned short* __restrict__ dst;
    int k0, n0, dstK;
    if (b < 16) {
        const int kt = b >> 1, nt = b & 1;
        k0 = kt * 64; n0 = nt * 64;
        src = W1; dst = W1T; dstK = IN_F;          // W1: 512k x 128n
    } else {
        const int bb = b - 16;
        const int kt = bb >> 1, nt = bb & 1;
        k0 = kt * 64; n0 = nt * 64;
        src = W2; dst = W2T; dstK = OUT_F;         // W2: 128k x 128n
    }

    for (int i = tid; i < 64 * 16; i += 256) {
        const int r = i >> 4, c4 = i & 15;
        float4 v = *reinterpret_cast<const float4*>(
            src + (size_t)(k0 + r) * OUT_F + n0 + c4 * 4);
        t[c4 * 4 + 0][r] = cvt_bf16_u(v.x);
        t[c4 * 4 + 1][r] = cvt_bf16_u(v.y);
        t[c4 * 4 + 2][r] = cvt_bf16_u(v.z);
        t[c4 * 4 + 3][r] = cvt_bf16_u(v.w);
    }
    __syncthreads();

    for (int i = tid; i < 64 * 16; i += 256) {
        const int n = i >> 4, c4 = i & 15;
        ushort4 v = *reinterpret_cast<const ushort4*>(&t[n][c4 * 4]);
        *reinterpret_cast<ushort4*>(
            dst + (size_t)(n0 + n) * dstK + k0 + c4 * 4) = v;
    }
}

// ---------------- K1: fused MLP projection (MFMA) + normalize + windowed KDE
//                      + softmax + per-block class partial sums (f32).
// 512 thr = 8 waves; 16 rows/block; 512 blocks.
__global__ __launch_bounds__(512) void fused_proj_pdf(
    const float* __restrict__ X1, const float* __restrict__ X2,
    const int* __restrict__ Y1, const int* __restrict__ Y2,
    const __hip_bfloat16* __restrict__ W1T, const float* __restrict__ b1,
    const __hip_bfloat16* __restrict__ W2T, const float* __restrict__ b2,
    const float* __restrict__ bins,
    float* __restrict__ partial, float* __restrict__ pcnt)
{
    __shared__ __hip_bfloat16 xb[16][IN_F + 8];   // 16.6 KB
    __shared__ __hip_bfloat16 h_lds[16][136];     // 4.3 KB
    __shared__ float pout[16][128];               // 8 KB
    __shared__ f32x4 rowMA[8][128];               // 16 KB (m0,m1,A0,A1) per dim
    __shared__ float smrows[16][128];             // 8 KB softmax rows (f32)
    __shared__ float bins_s[NBINS];               // 0.5 KB
    __shared__ int   labs[16];
    const int tid  = threadIdx.x;
    const int wave = tid >> 6;      // 0..7
    const int lane = tid & 63;
    const int lr   = lane & 15;
    const int kg   = lane >> 4;
    const int row0 = blockIdx.x * 16;
    const int batch = (row0 < NROWS) ? 0 : 1;
    const float* __restrict__ X = batch ? X2 : X1;
    const int* __restrict__ Y = batch ? Y2 : Y1;
    const int xr0 = batch ? row0 - NROWS : row0;
    const int col = wave * 16 + lr;

    if (tid < NBINS) bins_s[tid] = bins[tid];
    if (tid >= 128 && tid < 144) labs[tid - 128] = Y[xr0 + tid - 128];

    // ---- Phase 0: stage X tile (16 x 512 f32 -> bf16 LDS), coalesced ----
    for (int i = tid; i < 16 * 128; i += 512) {
        const int r = i >> 7, c4 = i & 127;
        float4 v = *reinterpret_cast<const float4*>(
            X + (size_t)(xr0 + r) * IN_F + c4 * 4);
        short4 s;
        s.x = cvt_bf16(v.x); s.y = cvt_bf16(v.y);
        s.z = cvt_bf16(v.z); s.w = cvt_bf16(v.w);
        *reinterpret_cast<short4*>(&xb[r][c4 * 4]) = s;
    }
    __syncthreads();

    // ---- GEMM1: (16 x 512) * (512 x 16 per wave) ----
    f32x4 acc = {0.f, 0.f, 0.f, 0.f};
    {
        const __hip_bfloat16* __restrict__ wrow = W1T + (size_t)col * IN_F;
        #pragma unroll 4
        for (int ks = 0; ks < IN_F / 32; ++ks) {
            const int kb = ks * 32 + kg * 8;
            bf16x8 a = *reinterpret_cast<const bf16x8*>(&xb[lr][kb]);
            bf16x8 b = *reinterpret_cast<const bf16x8*>(wrow + kb);
            acc = __builtin_amdgcn_mfma_f32_16x16x32_bf16(a, b, acc, 0, 0, 0);
        }
    }
    {
        const float bb = b1[col];
        #pragma unroll
        for (int q = 0; q < 4; ++q)
            h_lds[kg * 4 + q][col] = __float2bfloat16(fmaxf(acc[q] + bb, 0.f));
    }
    __syncthreads();

    // ---- GEMM2: (16 x 128) * (128 x 16 per wave) ----
    f32x4 c2 = {0.f, 0.f, 0.f, 0.f};
    {
        const __hip_bfloat16* __restrict__ w2row = W2T + (size_t)col * OUT_F;
        #pragma unroll
        for (int ks = 0; ks < OUT_F / 32; ++ks) {
            const int kb = ks * 32 + kg * 8;
            bf16x8 a2 = *reinterpret_cast<const bf16x8*>(&h_lds[lr][kb]);
            bf16x8 b2f = *reinterpret_cast<const bf16x8*>(w2row + kb);
            c2 = __builtin_amdgcn_mfma_f32_16x16x32_bf16(a2, b2f, c2, 0, 0, 0);
        }
    }
    {
        const float cb = b2[col];
        #pragma unroll
        for (int q = 0; q < 4; ++q)
            pout[kg * 4 + q][col] = c2[q] + cb;
    }
    __syncthreads();

    // ---- PDF phase: wave handles rows {2*wave, 2*wave+1} ----
    const int m0 = wave * 2, m1 = m0 + 1;

    const float p00 = pout[m0][lane], p01 = pout[m0][lane + 64];
    const float p10 = pout[m1][lane], p11 = pout[m1][lane + 64];

    float s0 = p00 * p00 + p01 * p01;
    float s1 = p10 * p10 + p11 * p11;
    #pragma unroll
    for (int off = 32; off; off >>= 1) {
        s0 += __shfl_xor(s0, off);
        s1 += __shfl_xor(s1, off);
    }
    const float i0 = __frsqrt_rn(s0), i1 = __frsqrt_rn(s1);
    const float x00 = p00 * i0, x01 = p01 * i0;
    const float x10 = p10 * i1, x11 = p11 * i1;

    // per-dim table: (m_r0, m_r1, A_r0, A_r1); arg_r = m_r*bj + (A_r + Bj)
    rowMA[wave][lane]      = (f32x4){x00 * M2C, x10 * M2C,
                                     C2EXP * x00 * x00, C2EXP * x10 * x10};
    rowMA[wave][lane + 64] = (f32x4){x01 * M2C, x11 * M2C,
                                     C2EXP * x01 * x01, C2EXP * x11 * x11};
    // wave-private LDS, lockstep wave64: compiler orders via lgkmcnt

    // window over both rows: |x|<=1 guarantees imax-imin <= 61 < 64
    float xlo = fminf(fminf(x00, x01), fminf(x10, x11));
    float xhi = fmaxf(fmaxf(x00, x01), fmaxf(x10, x11));
    #pragma unroll
    for (int off = 32; off; off >>= 1) {
        xlo = fminf(xlo, __shfl_xor(xlo, off));
        xhi = fmaxf(xhi, __shfl_xor(xhi, off));
    }
    int imin = (int)floorf((xlo + 5.0f) * INV_STEP) - WRAD;
    int imax = (int)ceilf ((xhi + 5.0f) * INV_STEP) + WRAD;
    imin = imin < 0 ? 0 : (imin > 127 ? 127 : imin);
    imax = imax > 127 ? 127 : (imax < 0 ? 0 : imax);
    if (imax > imin + 63) imax = imin + 63;   // provably never triggers
    const int nact = imax - imin + 1;
    const int j = imin + lane;
    const bool act = (j <= imax);
    const float bj = bins_s[act ? j : imax];
    const float Bj = C2EXP * bj * bj;
    const f32x2 BJ2 = {bj, bj};
    const f32x2 BB2 = {Bj, Bj};

    // KDE hot loop: per dim = 1 b128 read, pk_add, pk_fma, 2 exp, pk_acc.
    const f32x4* __restrict__ tb = &rowMA[wave][0];
    f32x2 accP = {0.f, 0.f};      // rows 0,1 accumulator (packed)
    f32x2 accQ = {0.f, 0.f};      // second chain
    #pragma unroll 8
    for (int d = 0; d < 128; d += 2) {
        f32x4 e0 = tb[d];                       // (m0, m1, A0, A1) dim d
        f32x4 e1 = tb[d + 1];                   // dim d+1
        f32x2 g0 = (f32x2){e0[0], e0[1]} * BJ2 + ((f32x2){e0[2], e0[3]} + BB2);
        f32x2 g1 = (f32x2){e1[0], e1[1]} * BJ2 + ((f32x2){e1[2], e1[3]} + BB2);
        accP += (f32x2){EXP2F(g0.x), EXP2F(g0.y)};
        accQ += (f32x2){EXP2F(g1.x), EXP2F(g1.y)};
    }
    float pdf0 = act ? (accP.x + accQ.x) * (1.0f / OUT_F) : 0.f;
    float pdf1 = act ? (accP.y + accQ.y) * (1.0f / OUT_F) : 0.f;

    // normalize over all 128 bins (out-of-window bins are exactly 0)
    float t0 = pdf0, t1 = pdf1;
    #pragma unroll
    for (int off = 32; off; off >>= 1) {
        t0 += __shfl_xor(t0, off);
        t1 += __shfl_xor(t1, off);
    }
    pdf0 *= 1.0f / (t0 + EPSV);
    pdf1 *= 1.0f / (t1 + EPSV);

    // softmax WITHOUT max subtraction: pdf in [0,1] so exp(pdf) in [1,e] —
    // exactly equal to the max-subtracted form in exact arithmetic.
    const float q0 = act ? __expf(pdf0) : 0.f;
    const float q1 = act ? __expf(pdf1) : 0.f;
    float es0 = q0, es1 = q1;
    #pragma unroll
    for (int off = 32; off; off >>= 1) {
        es0 += __shfl_xor(es0, off);
        es1 += __shfl_xor(es1, off);
    }
    es0 += (float)(NBINS - nact);    // zero-bins contribute exp(0) = 1
    es1 += (float)(NBINS - nact);
    const float r0 = 1.0f / es0, r1 = 1.0f / es1;
    const float z0 = r0, z1 = r1;    // exp(0) / es

    // scatter windowed values to output bins {lane, lane+64} -> LDS (f32)
    const int sa = lane - imin;
    const int sb = lane + 64 - imin;
    const float w0a = __shfl(q0, sa & 63) * r0;
    const float w0b = __shfl(q0, sb & 63) * r0;
    const float w1a = __shfl(q1, sa & 63) * r1;
    const float w1b = __shfl(q1, sb & 63) * r1;
    const bool ina = (unsigned)sa < (unsigned)nact;
    const bool inb = (unsigned)sb < (unsigned)nact;

    smrows[m0][lane]      = ina ? w0a : z0;
    smrows[m0][lane + 64] = inb ? w0b : z0;
    smrows[m1][lane]      = ina ? w1a : z1;
    smrows[m1][lane + 64] = inb ? w1b : z1;
    __syncthreads();

    // ---- classsum: thread = (class, j-quad); 16 rows, predicated fma ----
    {
        const int c_cls = tid >> 5;       // 0..15
        const int jq    = tid & 31;       // 0..31
        f32x4 accp = {0.f, 0.f, 0.f, 0.f};
        int ccnt = 0;
        #pragma unroll 4
        for (int r = 0; r < 16; ++r) {
            const float4 v = *reinterpret_cast<const float4*>(&smrows[r][jq * 4]);
            const float h = (labs[r] == c_cls) ? 1.f : 0.f;
            accp.x = fmaf(h, v.x, accp.x);
            accp.y = fmaf(h, v.y, accp.y);
            accp.z = fmaf(h, v.z, accp.z);
            accp.w = fmaf(h, v.w, accp.w);
            ccnt += (labs[r] == c_cls);
        }
        *reinterpret_cast<f32x4*>(
            &partial[(size_t)blockIdx.x * PSTRIDE + c_cls * NBINS + jq * 4]) = accp;
        if (jq == 0) pcnt[(size_t)blockIdx.x * NCLS + c_cls] = (float)ccnt;
    }
}

// ---------------- K2: merge 256 per-block partials per batch -> dist --------
__global__ __launch_bounds__(256) void merge_kernel(
    const float* __restrict__ partial, const float* __restrict__ pcnt,
    float* __restrict__ dist, float* __restrict__ cntg)
{
    __shared__ float sd[16][17];     // +1 pad
    __shared__ float sc[4];
    const int b = blockIdx.x;             // 0..255
    const int bc = b >> 3, jg = b & 7;
    const int batch = bc >> 4, c = bc & 15;
    const int j0 = jg * 16;
    const int tid = threadIdx.x;
    const int jl = tid & 15, s = tid >> 4;   // s 0..15

    float acc = 0.f;
    #pragma unroll 4
    for (int k = 0; k < 16; ++k) {
        const int sb = s + k * 16;           // source block within batch
        acc += partial[(size_t)(batch * 256 + sb) * PSTRIDE + c * NBINS + j0 + jl];
    }
    sd[s][jl] = acc;

    // counts: only jg==0 blocks do the work
    if (jg == 0) {
        float cv = pcnt[(size_t)(batch * 256 + tid) * NCLS + c];
        #pragma unroll
        for (int off = 32; off; off >>= 1) cv += __shfl_xor(cv, off);
        if ((tid & 63) == 0) sc[tid >> 6] = cv;
    }
    __syncthreads();

    if (tid < 16) {
        float d = 0.f;
        #pragma unroll
        for (int q = 0; q < 16; ++q) d += sd[q][tid];
        dist[(size_t)bc * NBINS + j0 + tid] = d;
    }
    if (jg == 0 && tid == 0) cntg[bc] = sc[0] + sc[1] + sc[2] + sc[3];
}

// ---------------- K3: means, logs, tiled KL, loss ---------------------------
__global__ __launch_bounds__(512) void final_kernel(
    const float* __restrict__ dist, const float* __restrict__ cntg,
    float* __restrict__ out)
{
    __shared__ float P_A[32][132], L_A[32][132];   // 2 x 16.5 KB
    __shared__ float P_B[32][132], L_B[32][132];   // 2 x 16.5 KB
    __shared__ float JA[32][32], JB[32][32];       // 8 KB
    __shared__ float pls[32];
    __shared__ float cnt[32];
    __shared__ float HA[32], HB[32];
    const int tid = threadIdx.x;

    if (tid < 32) cnt[tid] = cntg[tid];
    __syncthreads();

    for (int s = tid; s < NCLS * NBINS; s += 512) {
        const int c = s >> 7, jj = s & 127;
        const float a = dist[(size_t)c * NBINS + jj] / cnt[c];
        const float b = dist[(size_t)(16 + c) * NBINS + jj] / cnt[16 + c];
        const float mm = 0.5f * (a + b);
        const float lm = __logf(mm);
        P_A[c][jj] = a;        L_A[c][jj] = __logf(a);
        P_A[c + 16][jj] = mm;  L_A[c + 16][jj] = lm;
        P_B[c][jj] = b;        L_B[c][jj] = __logf(b);
        P_B[c + 16][jj] = mm;  L_B[c + 16][jj] = lm;
    }
    __syncthreads();

    if (tid < 64) {
        const int i = tid & 31;
        const float4* Pv = reinterpret_cast<const float4*>(
            (tid < 32) ? &P_A[i][0] : &P_B[i][0]);
        const float4* Lv = reinterpret_cast<const float4*>(
            (tid < 32) ? &L_A[i][0] : &L_B[i][0]);
        float h = 0.f;
        #pragma unroll 4
        for (int q = 0; q < 32; ++q) {
            float4 p = Pv[q], l = Lv[q];
            h = fmaf(p.x, l.x, h); h = fmaf(p.y, l.y, h);
            h = fmaf(p.z, l.z, h); h = fmaf(p.w, l.w, h);
        }
        if (tid < 32) HA[i] = h; else HB[i] = h;
    }
    __syncthreads();

    // KL cross terms: 2x4 register tile per thread on 4 waves (256 threads):
    // halves per-thread serial LDS chain vs the 2-wave 4x4 tiling.
    if (tid < 256) {
        const int side = tid >> 7;            // 0 = A, 1 = B
        const int t = tid & 127;
        const int i0 = (t >> 3) << 1;         // 16 groups of 2 rows
        const int k0 = (t & 7) << 2;          // 8 groups of 4 cols
        const float4* pr[2];
        const float4* lq[4];
        #pragma unroll
        for (int a = 0; a < 2; ++a)
            pr[a] = reinterpret_cast<const float4*>(
                side ? &P_B[i0 + a][0] : &P_A[i0 + a][0]);
        #pragma unroll
        for (int b = 0; b < 4; ++b)
            lq[b] = reinterpret_cast<const float4*>(
                side ? &L_B[k0 + b][0] : &L_A[k0 + b][0]);
        float accv[2][4];
        #pragma unroll
        for (int a = 0; a < 2; ++a)
            #pragma unroll
            for (int b = 0; b < 4; ++b) accv[a][b] = 0.f;
        for (int q = 0; q < 32; ++q) {
            float4 Pv[2], Lv[4];
            #pragma unroll
            for (int a = 0; a < 2; ++a) Pv[a] = pr[a][q];
            #pragma unroll
            for (int b = 0; b < 4; ++b) Lv[b] = lq[b][q];
            #pragma unroll
            for (int a = 0; a < 2; ++a)
                #pragma unroll
                for (int b = 0; b < 4; ++b) {
                    accv[a][b] = fmaf(Pv[a].x, Lv[b].x, accv[a][b]);
                    accv[a][b] = fmaf(Pv[a].y, Lv[b].y, accv[a][b]);
                    accv[a][b] = fmaf(Pv[a].z, Lv[b].z, accv[a][b]);
                    accv[a][b] = fmaf(Pv[a].w, Lv[b].w, accv[a][b]);
                }
        }
        float (*Jout)[32] = side ? JB : JA;
        #pragma unroll
        for (int a = 0; a < 2; ++a)
            #pragma unroll
            for (int b = 0; b < 4; ++b)
                Jout[i0 + a][k0 + b] = accv[a][b];
    }
    __syncthreads();

    for (int p = tid; p < 32 * 32; p += 512) {
        const int i = p >> 5, k = p & 31;
        const float Jv = (i == k) ? 0.f
            : 0.5f * ((HA[i] - JA[i][k]) + (HB[i] - JB[i][k]));
        JA[i][k] = Jv;
    }
    __syncthreads();

    if (tid < 32) {
        float den = 0.f;
        for (int k = 0; k < 32; ++k) den += __expf(JA[tid][k] * (1.0f / TAUV));
        const float pos = JA[tid][(tid + 16) & 31];
        pls[tid] = -(pos * (1.0f / TAUV)) + __logf(den);
    }
    __syncthreads();
    if (tid == 0) {
        float s = 0.f;
        for (int i = 0; i < 32; ++i) s += pls[i];
        out[0] = s * (1.0f / 32.0f);
    }
}

extern "C" void kernel_launch(void* const* d_in, const int* in_sizes, int n_in,
                              void* d_out, int out_size, void* d_ws, size_t ws_size,
                              hipStream_t stream)
{
    const float* x1   = (const float*)d_in[0];
    const int*   y1   = (const int*)d_in[1];
    const float* x2   = (const float*)d_in[2];
    const int*   y2   = (const int*)d_in[3];
    const float* W1   = (const float*)d_in[4];
    const float* b1   = (const float*)d_in[5];
    const float* W2   = (const float*)d_in[6];
    const float* b2   = (const float*)d_in[7];
    const float* bins = (const float*)d_in[8];
    float* out = (float*)d_out;

    char* ws = (char*)d_ws;
    float* partial = (float*)ws;                                   // 512*PSTRIDE*4 ≈ 4.3 MB
    float* pcnt    = partial + (size_t)512 * PSTRIDE;              // 512*16 f32
    float* dist    = pcnt + 512 * NCLS;                            // 32*128 f32
    float* cntg    = dist + 32 * NBINS;                            // 32 f32
    unsigned short* W1T = (unsigned short*)(cntg + 64);
    unsigned short* W2T = W1T + (size_t)OUT_F * IN_F;

    prep_w<<<20, 256, 0, stream>>>(W1, W2, W1T, W2T);
    fused_proj_pdf<<<512, 512, 0, stream>>>(x1, x2, y1, y2,
                                            (const __hip_bfloat16*)W1T, b1,
                                            (const __hip_bfloat16*)W2T, b2,
                                            bins, partial, pcnt);
    merge_kernel<<<256, 256, 0, stream>>>(partial, pcnt, dist, cntg);
    final_kernel<<<1, 512, 0, stream>>>(dist, cntg, out);
}

// Round 24
// 44.093 us; speedup vs baseline: 1.0857x; 1.0099x over previous
//
#include <hip/hip_runtime.h>
#include <hip/hip_bf16.h>

#define NROWS 4096
#define IN_F 512
#define OUT_F 128
#define NBINS 128
#define NCLS 16
#define EPSV 1e-8f
#define TAUV 0.1f
#define PSTRIDE (NCLS * NBINS + 32)   // padded per-block partial stride (bf16 elems)

// C2EXP = -0.5 / sigma^2 * log2(e),  sigma = 0.2
#define C2EXP (-18.0336880f)
#define M2C   (36.0673760f)   // -2 * C2EXP
#define INV_STEP (12.7f)      // 127 / 10  (bins = linspace(-5,5,128))
#define WRAD 17               // window radius in bins (arg < -36 beyond)

#if defined(__has_builtin)
#if __has_builtin(__builtin_amdgcn_exp2f)
#define EXP2F(x) __builtin_amdgcn_exp2f(x)
#else
#define EXP2F(x) exp2f(x)
#endif
#else
#define EXP2F(x) exp2f(x)
#endif

typedef __attribute__((ext_vector_type(8))) short bf16x8;
typedef __attribute__((ext_vector_type(4))) float f32x4;
typedef __attribute__((ext_vector_type(2))) float f32x2;

__device__ __forceinline__ short cvt_bf16(float x) {
    __hip_bfloat16 h = __float2bfloat16(x);
    return *reinterpret_cast<short*>(&h);
}
__device__ __forceinline__ unsigned short cvt_bf16_u(float x) {
    __hip_bfloat16 h = __float2bfloat16(x);
    return *reinterpret_cast<unsigned short*>(&h);
}
__device__ __forceinline__ float bf_to_f(unsigned short u) {
    return __uint_as_float((unsigned int)u << 16);
}

// ---------------- K0: tiled transpose + convert weights to bf16 -------------
__global__ __launch_bounds__(256) void prep_w(
    const float* __restrict__ W1, const float* __restrict__ W2,
    unsigned short* __restrict__ W1T, unsigned short* __restrict__ W2T)
{
    __shared__ unsigned short t[64][68];   // 64k x 64n tile, padded
    const int b = blockIdx.x;
    const int tid = threadIdx.x;

    const float* __restrict__ src;
    unsigned short* __restrict__ dst;
    int k0, n0, dstK;
    if (b < 16) {
        const int kt = b >> 1, nt = b & 1;
        k0 = kt * 64; n0 = nt * 64;
        src = W1; dst = W1T; dstK = IN_F;          // W1: 512k x 128n
    } else {
        const int bb = b - 16;
        const int kt = bb >> 1, nt = bb & 1;
        k0 = kt * 64; n0 = nt * 64;
        src = W2; dst = W2T; dstK = OUT_F;         // W2: 128k x 128n
    }

    for (int i = tid; i < 64 * 16; i += 256) {
        const int r = i >> 4, c4 = i & 15;
        float4 v = *reinterpret_cast<const float4*>(
            src + (size_t)(k0 + r) * OUT_F + n0 + c4 * 4);
        t[c4 * 4 + 0][r] = cvt_bf16_u(v.x);
        t[c4 * 4 + 1][r] = cvt_bf16_u(v.y);
        t[c4 * 4 + 2][r] = cvt_bf16_u(v.z);
        t[c4 * 4 + 3][r] = cvt_bf16_u(v.w);
    }
    __syncthreads();

    for (int i = tid; i < 64 * 16; i += 256) {
        const int n = i >> 4, c4 = i & 15;
        ushort4 v = *reinterpret_cast<const ushort4*>(&t[n][c4 * 4]);
        *reinterpret_cast<ushort4*>(
            dst + (size_t)(n0 + n) * dstK + k0 + c4 * 4) = v;
    }
}

// ---------------- K1: fused MLP projection (MFMA) + normalize + windowed KDE
//                      + softmax + per-block class partial sums (bf16 out).
// 512 thr = 8 waves; 16 rows/block; 512 blocks.
__global__ __launch_bounds__(512) void fused_proj_pdf(
    const float* __restrict__ X1, const float* __restrict__ X2,
    const int* __restrict__ Y1, const int* __restrict__ Y2,
    const __hip_bfloat16* __restrict__ W1T, const float* __restrict__ b1,
    const __hip_bfloat16* __restrict__ W2T, const float* __restrict__ b2,
    const float* __restrict__ bins,
    unsigned short* __restrict__ partial, float* __restrict__ pcnt)
{
    __shared__ __hip_bfloat16 xb[16][IN_F + 8];   // 16.6 KB
    __shared__ __hip_bfloat16 h_lds[16][136];     // 4.3 KB
    __shared__ float pout[16][128];               // 8 KB
    __shared__ f32x4 rowMA[8][128];               // 16 KB (m0,m1,A0,A1) per dim
    __shared__ float smrows[16][128];             // 8 KB softmax rows (f32)
    __shared__ float bins_s[NBINS];               // 0.5 KB
    __shared__ int   labs[16];
    const int tid  = threadIdx.x;
    const int wave = tid >> 6;      // 0..7
    const int lane = tid & 63;
    const int lr   = lane & 15;
    const int kg   = lane >> 4;
    const int row0 = blockIdx.x * 16;
    const int batch = (row0 < NROWS) ? 0 : 1;
    const float* __restrict__ X = batch ? X2 : X1;
    const int* __restrict__ Y = batch ? Y2 : Y1;
    const int xr0 = batch ? row0 - NROWS : row0;
    const int col = wave * 16 + lr;

    if (tid < NBINS) bins_s[tid] = bins[tid];
    if (tid >= 128 && tid < 144) labs[tid - 128] = Y[xr0 + tid - 128];

    // ---- Phase 0: stage X tile (16 x 512 f32 -> bf16 LDS), coalesced ----
    for (int i = tid; i < 16 * 128; i += 512) {
        const int r = i >> 7, c4 = i & 127;
        float4 v = *reinterpret_cast<const float4*>(
            X + (size_t)(xr0 + r) * IN_F + c4 * 4);
        short4 s;
        s.x = cvt_bf16(v.x); s.y = cvt_bf16(v.y);
        s.z = cvt_bf16(v.z); s.w = cvt_bf16(v.w);
        *reinterpret_cast<short4*>(&xb[r][c4 * 4]) = s;
    }
    __syncthreads();

    // ---- GEMM1: (16 x 512) * (512 x 16 per wave) ----
    f32x4 acc = {0.f, 0.f, 0.f, 0.f};
    {
        const __hip_bfloat16* __restrict__ wrow = W1T + (size_t)col * IN_F;
        #pragma unroll 4
        for (int ks = 0; ks < IN_F / 32; ++ks) {
            const int kb = ks * 32 + kg * 8;
            bf16x8 a = *reinterpret_cast<const bf16x8*>(&xb[lr][kb]);
            bf16x8 b = *reinterpret_cast<const bf16x8*>(wrow + kb);
            acc = __builtin_amdgcn_mfma_f32_16x16x32_bf16(a, b, acc, 0, 0, 0);
        }
    }
    {
        const float bb = b1[col];
        #pragma unroll
        for (int q = 0; q < 4; ++q)
            h_lds[kg * 4 + q][col] = __float2bfloat16(fmaxf(acc[q] + bb, 0.f));
    }
    __syncthreads();

    // ---- GEMM2: (16 x 128) * (128 x 16 per wave) ----
    f32x4 c2 = {0.f, 0.f, 0.f, 0.f};
    {
        const __hip_bfloat16* __restrict__ w2row = W2T + (size_t)col * OUT_F;
        #pragma unroll
        for (int ks = 0; ks < OUT_F / 32; ++ks) {
            const int kb = ks * 32 + kg * 8;
            bf16x8 a2 = *reinterpret_cast<const bf16x8*>(&h_lds[lr][kb]);
            bf16x8 b2f = *reinterpret_cast<const bf16x8*>(w2row + kb);
            c2 = __builtin_amdgcn_mfma_f32_16x16x32_bf16(a2, b2f, c2, 0, 0, 0);
        }
    }
    {
        const float cb = b2[col];
        #pragma unroll
        for (int q = 0; q < 4; ++q)
            pout[kg * 4 + q][col] = c2[q] + cb;
    }
    __syncthreads();

    // ---- PDF phase: wave handles rows {2*wave, 2*wave+1} ----
    const int m0 = wave * 2, m1 = m0 + 1;

    const float p00 = pout[m0][lane], p01 = pout[m0][lane + 64];
    const float p10 = pout[m1][lane], p11 = pout[m1][lane + 64];

    float s0 = p00 * p00 + p01 * p01;
    float s1 = p10 * p10 + p11 * p11;
    #pragma unroll
    for (int off = 32; off; off >>= 1) {
        s0 += __shfl_xor(s0, off);
        s1 += __shfl_xor(s1, off);
    }
    const float i0 = __frsqrt_rn(s0), i1 = __frsqrt_rn(s1);
    const float x00 = p00 * i0, x01 = p01 * i0;
    const float x10 = p10 * i1, x11 = p11 * i1;

    // per-dim table: (m_r0, m_r1, A_r0, A_r1); arg_r = m_r*bj + (A_r + Bj)
    rowMA[wave][lane]      = (f32x4){x00 * M2C, x10 * M2C,
                                     C2EXP * x00 * x00, C2EXP * x10 * x10};
    rowMA[wave][lane + 64] = (f32x4){x01 * M2C, x11 * M2C,
                                     C2EXP * x01 * x01, C2EXP * x11 * x11};
    // wave-private LDS, lockstep wave64: compiler orders via lgkmcnt

    // window over both rows: |x|<=1 guarantees imax-imin <= 61 < 64
    float xlo = fminf(fminf(x00, x01), fminf(x10, x11));
    float xhi = fmaxf(fmaxf(x00, x01), fmaxf(x10, x11));
    #pragma unroll
    for (int off = 32; off; off >>= 1) {
        xlo = fminf(xlo, __shfl_xor(xlo, off));
        xhi = fmaxf(xhi, __shfl_xor(xhi, off));
    }
    int imin = (int)floorf((xlo + 5.0f) * INV_STEP) - WRAD;
    int imax = (int)ceilf ((xhi + 5.0f) * INV_STEP) + WRAD;
    imin = imin < 0 ? 0 : (imin > 127 ? 127 : imin);
    imax = imax > 127 ? 127 : (imax < 0 ? 0 : imax);
    if (imax > imin + 63) imax = imin + 63;   // provably never triggers
    const int nact = imax - imin + 1;
    const int j = imin + lane;
    const bool act = (j <= imax);
    const float bj = bins_s[act ? j : imax];
    const float Bj = C2EXP * bj * bj;
    const f32x2 BJ2 = {bj, bj};
    const f32x2 BB2 = {Bj, Bj};

    // KDE hot loop: per dim = 1 b128 read, pk_add, pk_fma, 2 exp, pk_acc.
    const f32x4* __restrict__ tb = &rowMA[wave][0];
    f32x2 accP = {0.f, 0.f};
    f32x2 accQ = {0.f, 0.f};
    #pragma unroll 8
    for (int d = 0; d < 128; d += 2) {
        f32x4 e0 = tb[d];
        f32x4 e1 = tb[d + 1];
        f32x2 g0 = (f32x2){e0[0], e0[1]} * BJ2 + ((f32x2){e0[2], e0[3]} + BB2);
        f32x2 g1 = (f32x2){e1[0], e1[1]} * BJ2 + ((f32x2){e1[2], e1[3]} + BB2);
        accP += (f32x2){EXP2F(g0.x), EXP2F(g0.y)};
        accQ += (f32x2){EXP2F(g1.x), EXP2F(g1.y)};
    }
    float pdf0 = act ? (accP.x + accQ.x) * (1.0f / OUT_F) : 0.f;
    float pdf1 = act ? (accP.y + accQ.y) * (1.0f / OUT_F) : 0.f;

    // normalize over all 128 bins (out-of-window bins are exactly 0)
    float t0 = pdf0, t1 = pdf1;
    #pragma unroll
    for (int off = 32; off; off >>= 1) {
        t0 += __shfl_xor(t0, off);
        t1 += __shfl_xor(t1, off);
    }
    pdf0 *= 1.0f / (t0 + EPSV);
    pdf1 *= 1.0f / (t1 + EPSV);

    // softmax without max subtraction: pdf in [0,1] -> exp in [1,e]
    const float q0 = act ? __expf(pdf0) : 0.f;
    const float q1 = act ? __expf(pdf1) : 0.f;
    float es0 = q0, es1 = q1;
    #pragma unroll
    for (int off = 32; off; off >>= 1) {
        es0 += __shfl_xor(es0, off);
        es1 += __shfl_xor(es1, off);
    }
    es0 += (float)(NBINS - nact);    // zero-bins contribute exp(0) = 1
    es1 += (float)(NBINS - nact);
    const float r0 = 1.0f / es0, r1 = 1.0f / es1;
    const float z0 = r0, z1 = r1;

    // scatter windowed values to output bins {lane, lane+64} -> LDS (f32)
    const int sa = lane - imin;
    const int sb = lane + 64 - imin;
    const float w0a = __shfl(q0, sa & 63) * r0;
    const float w0b = __shfl(q0, sb & 63) * r0;
    const float w1a = __shfl(q1, sa & 63) * r1;
    const float w1b = __shfl(q1, sb & 63) * r1;
    const bool ina = (unsigned)sa < (unsigned)nact;
    const bool inb = (unsigned)sb < (unsigned)nact;

    smrows[m0][lane]      = ina ? w0a : z0;
    smrows[m0][lane + 64] = inb ? w0b : z0;
    smrows[m1][lane]      = ina ? w1a : z1;
    smrows[m1][lane + 64] = inb ? w1b : z1;
    __syncthreads();

    // ---- classsum: thread = (class, j-quad); 16 rows, predicated fma ----
    {
        const int c_cls = tid >> 5;       // 0..15
        const int jq    = tid & 31;       // 0..31
        f32x4 accp = {0.f, 0.f, 0.f, 0.f};
        int ccnt = 0;
        #pragma unroll 4
        for (int r = 0; r < 16; ++r) {
            const float4 v = *reinterpret_cast<const float4*>(&smrows[r][jq * 4]);
            const float h = (labs[r] == c_cls) ? 1.f : 0.f;
            accp.x = fmaf(h, v.x, accp.x);
            accp.y = fmaf(h, v.y, accp.y);
            accp.z = fmaf(h, v.z, accp.z);
            accp.w = fmaf(h, v.w, accp.w);
            ccnt += (labs[r] == c_cls);
        }
        ushort4 o;
        o.x = cvt_bf16_u(accp.x); o.y = cvt_bf16_u(accp.y);
        o.z = cvt_bf16_u(accp.z); o.w = cvt_bf16_u(accp.w);
        *reinterpret_cast<ushort4*>(
            &partial[(size_t)blockIdx.x * PSTRIDE + c_cls * NBINS + jq * 4]) = o;
        if (jq == 0) pcnt[(size_t)blockIdx.x * NCLS + c_cls] = (float)ccnt;
    }
}

// ---------------- K2: merge 256 per-block bf16 partials per batch -> dist ---
__global__ __launch_bounds__(256) void merge_kernel(
    const unsigned short* __restrict__ partial, const float* __restrict__ pcnt,
    float* __restrict__ dist, float* __restrict__ cntg)
{
    __shared__ float sd[16][17];     // +1 pad
    __shared__ float sc[4];
    const int b = blockIdx.x;             // 0..255
    const int bc = b >> 3, jg = b & 7;
    const int batch = bc >> 4, c = bc & 15;
    const int j0 = jg * 16;
    const int tid = threadIdx.x;
    const int jl = tid & 15, s = tid >> 4;   // s 0..15

    float acc = 0.f;
    #pragma unroll 4
    for (int k = 0; k < 16; ++k) {
        const int sb = s + k * 16;           // source block within batch
        acc += bf_to_f(partial[(size_t)(batch * 256 + sb) * PSTRIDE
                               + c * NBINS + j0 + jl]);
    }
    sd[s][jl] = acc;

    // counts: only jg==0 blocks do the work
    if (jg == 0) {
        float cv = pcnt[(size_t)(batch * 256 + tid) * NCLS + c];
        #pragma unroll
        for (int off = 32; off; off >>= 1) cv += __shfl_xor(cv, off);
        if ((tid & 63) == 0) sc[tid >> 6] = cv;
    }
    __syncthreads();

    if (tid < 16) {
        float d = 0.f;
        #pragma unroll
        for (int q = 0; q < 16; ++q) d += sd[q][tid];
        dist[(size_t)bc * NBINS + j0 + tid] = d;
    }
    if (jg == 0 && tid == 0) cntg[bc] = sc[0] + sc[1] + sc[2] + sc[3];
}

// ---------------- K3: means, logs, tiled KL, loss ---------------------------
__global__ __launch_bounds__(512) void final_kernel(
    const float* __restrict__ dist, const float* __restrict__ cntg,
    float* __restrict__ out)
{
    __shared__ float P_A[32][132], L_A[32][132];   // 2 x 16.5 KB
    __shared__ float P_B[32][132], L_B[32][132];   // 2 x 16.5 KB
    __shared__ float JA[32][32], JB[32][32];       // 8 KB
    __shared__ float pls[32];
    __shared__ float cnt[32];
    __shared__ float HA[32], HB[32];
    const int tid = threadIdx.x;

    if (tid < 32) cnt[tid] = cntg[tid];
    __syncthreads();

    for (int s = tid; s < NCLS * NBINS; s += 512) {
        const int c = s >> 7, jj = s & 127;
        const float a = dist[(size_t)c * NBINS + jj] / cnt[c];
        const float b = dist[(size_t)(16 + c) * NBINS + jj] / cnt[16 + c];
        const float mm = 0.5f * (a + b);
        const float lm = __logf(mm);
        P_A[c][jj] = a;        L_A[c][jj] = __logf(a);
        P_A[c + 16][jj] = mm;  L_A[c + 16][jj] = lm;
        P_B[c][jj] = b;        L_B[c][jj] = __logf(b);
        P_B[c + 16][jj] = mm;  L_B[c + 16][jj] = lm;
    }
    __syncthreads();

    if (tid < 64) {
        const int i = tid & 31;
        const float4* Pv = reinterpret_cast<const float4*>(
            (tid < 32) ? &P_A[i][0] : &P_B[i][0]);
        const float4* Lv = reinterpret_cast<const float4*>(
            (tid < 32) ? &L_A[i][0] : &L_B[i][0]);
        float h = 0.f;
        #pragma unroll 4
        for (int q = 0; q < 32; ++q) {
            float4 p = Pv[q], l = Lv[q];
            h = fmaf(p.x, l.x, h); h = fmaf(p.y, l.y, h);
            h = fmaf(p.z, l.z, h); h = fmaf(p.w, l.w, h);
        }
        if (tid < 32) HA[i] = h; else HB[i] = h;
    }
    __syncthreads();

    // KL cross terms: 2x4 register tile per thread on 4 waves (256 threads)
    if (tid < 256) {
        const int side = tid >> 7;            // 0 = A, 1 = B
        const int t = tid & 127;
        const int i0 = (t >> 3) << 1;         // 16 groups of 2 rows
        const int k0 = (t & 7) << 2;          // 8 groups of 4 cols
        const float4* pr[2];
        const float4* lq[4];
        #pragma unroll
        for (int a = 0; a < 2; ++a)
            pr[a] = reinterpret_cast<const float4*>(
                side ? &P_B[i0 + a][0] : &P_A[i0 + a][0]);
        #pragma unroll
        for (int b = 0; b < 4; ++b)
            lq[b] = reinterpret_cast<const float4*>(
                side ? &L_B[k0 + b][0] : &L_A[k0 + b][0]);
        float accv[2][4];
        #pragma unroll
        for (int a = 0; a < 2; ++a)
            #pragma unroll
            for (int b = 0; b < 4; ++b) accv[a][b] = 0.f;
        for (int q = 0; q < 32; ++q) {
            float4 Pv[2], Lv[4];
            #pragma unroll
            for (int a = 0; a < 2; ++a) Pv[a] = pr[a][q];
            #pragma unroll
            for (int b = 0; b < 4; ++b) Lv[b] = lq[b][q];
            #pragma unroll
            for (int a = 0; a < 2; ++a)
                #pragma unroll
                for (int b = 0; b < 4; ++b) {
                    accv[a][b] = fmaf(Pv[a].x, Lv[b].x, accv[a][b]);
                    accv[a][b] = fmaf(Pv[a].y, Lv[b].y, accv[a][b]);
                    accv[a][b] = fmaf(Pv[a].z, Lv[b].z, accv[a][b]);
                    accv[a][b] = fmaf(Pv[a].w, Lv[b].w, accv[a][b]);
                }
        }
        float (*Jout)[32] = side ? JB : JA;
        #pragma unroll
        for (int a = 0; a < 2; ++a)
            #pragma unroll
            for (int b = 0; b < 4; ++b)
                Jout[i0 + a][k0 + b] = accv[a][b];
    }
    __syncthreads();

    for (int p = tid; p < 32 * 32; p += 512) {
        const int i = p >> 5, k = p & 31;
        const float Jv = (i == k) ? 0.f
            : 0.5f * ((HA[i] - JA[i][k]) + (HB[i] - JB[i][k]));
        JA[i][k] = Jv;
    }
    __syncthreads();

    if (tid < 32) {
        float den = 0.f;
        for (int k = 0; k < 32; ++k) den += __expf(JA[tid][k] * (1.0f / TAUV));
        const float pos = JA[tid][(tid + 16) & 31];
        pls[tid] = -(pos * (1.0f / TAUV)) + __logf(den);
    }
    __syncthreads();
    if (tid == 0) {
        float s = 0.f;
        for (int i = 0; i < 32; ++i) s += pls[i];
        out[0] = s * (1.0f / 32.0f);
    }
}

extern "C" void kernel_launch(void* const* d_in, const int* in_sizes, int n_in,
                              void* d_out, int out_size, void* d_ws, size_t ws_size,
                              hipStream_t stream)
{
    const float* x1   = (const float*)d_in[0];
    const int*   y1   = (const int*)d_in[1];
    const float* x2   = (const float*)d_in[2];
    const int*   y2   = (const int*)d_in[3];
    const float* W1   = (const float*)d_in[4];
    const float* b1   = (const float*)d_in[5];
    const float* W2   = (const float*)d_in[6];
    const float* b2   = (const float*)d_in[7];
    const float* bins = (const float*)d_in[8];
    float* out = (float*)d_out;

    char* ws = (char*)d_ws;
    unsigned short* partial = (unsigned short*)ws;                 // 512*PSTRIDE bf16 ≈ 2.1 MB
    float* pcnt = (float*)(ws + (size_t)512 * PSTRIDE * 2);        // 512*16 f32
    float* dist = pcnt + 512 * NCLS;                               // 32*128 f32
    float* cntg = dist + 32 * NBINS;                               // 32 f32
    unsigned short* W1T = (unsigned short*)(cntg + 64);
    unsigned short* W2T = W1T + (size_t)OUT_F * IN_F;

    prep_w<<<20, 256, 0, stream>>>(W1, W2, W1T, W2T);
    fused_proj_pdf<<<512, 512, 0, stream>>>(x1, x2, y1, y2,
                                            (const __hip_bfloat16*)W1T, b1,
                                            (const __hip_bfloat16*)W2T, b2,
                                            bins, partial, pcnt);
    merge_kernel<<<256, 256, 0, stream>>>(partial, pcnt, dist, cntg);
    final_kernel<<<1, 512, 0, stream>>>(dist, cntg, out);
}